// Round 12
// baseline (455.735 us; speedup 1.0000x reference)
//
#include <hip/hip_runtime.h>
#include <math.h>

#define BB 64
#define NN 207
#define TT 12
#define NC 10
#define NP 208              // padded matrix dim (pad row 207: identity)
#define TRIP 22048          // 4-aligned packed lower triangle
#define QTOT 5512           // TRIP/4 quad-chunks for staging
#define WR 32               // RHS rows per block
#define WST 212             // W row stride
#define PTS 244             // Pt row stride (rho max 239)
#define LST 36              // ldg row stride (f4-aligned, non-pow2: 4-way not 32-way)
#define KDT 512
#define NBLK 240
#define NKS 910             // k1 Ks tile blocks

// ws layout (float offsets).
#define KS_OFF   0          // [C][N][N]       428490
#define DT_OFF   428490     // [C][T]          120
#define UT_OFF   428610     // [C][T][T]       1440
#define ULOG_OFF 430050
#define VLOG_OFF 430060
#define CNT_OFF  430070
#define MAEC_OFF 430071
#define MAEA_OFF 430135
#define SSQ_OFF  430199     // [C][T][B]       7680

__device__ __forceinline__ int roff(int r) {
    return ((r*(r+1)) >> 1) + 6*(r >> 2) + ((0x6530 >> ((r & 3) << 2)) & 15);
}

__device__ __forceinline__ void WB() {
    __builtin_amdgcn_wave_barrier();
    __asm__ volatile("" ::: "memory");
}

__device__ inline void jpair(int r, int pi, int& p, int& q) {
    if (pi == 0) { p = 11; q = r % 11; }
    else { p = (r + pi) % 11; q = (r + 11 - pi) % 11; }
}

// k1: unchanged (Ks tiles + Jacobi + MAE partials)
__global__ __launch_bounds__(256) void k1(const float* __restrict__ Ls,
                                          const float* __restrict__ Lt,
                                          const float* __restrict__ mu,
                                          const float* __restrict__ tg,
                                          const float* __restrict__ uns,
                                          float* __restrict__ ws) {
    __shared__ float sh[1216];
    int t = threadIdx.x;
    int blk = blockIdx.x;
    if (blk < NKS) {
        int c = blk / 91, r = blk % 91;
        int it = (int)((sqrtf(8.f*r + 1.f) - 1.f)*0.5f);
        while ((it+1)*(it+2)/2 <= r) ++it;
        while (it*(it+1)/2 > r) --it;
        int jt = r - it*(it+1)/2;
        int I0 = it*16, J0 = jt*16;
        float* As = sh;
        float* Bs = sh + 272;
        int ti = t >> 4, tj = t & 15;
        int srow = t >> 4, skk = t & 15;
        float acc = 0.f;
        for (int kc = 0; kc <= jt; ++kc) {
            int k = kc*16 + skk;
            int ia = I0 + srow, jb = J0 + srow;
            As[srow*17 + skk] = (ia < NN && k < NN) ? Ls[(size_t)(c*NN + ia)*NN + k] : 0.f;
            Bs[srow*17 + skk] = (jb < NN && k < NN) ? Ls[(size_t)(c*NN + jb)*NN + k] : 0.f;
            __syncthreads();
            #pragma unroll
            for (int kk = 0; kk < 16; ++kk)
                acc += As[ti*17 + kk] * Bs[tj*17 + kk];
            __syncthreads();
        }
        int I = I0 + ti, J = J0 + tj;
        if (I < NN && J < NN)
            ws[KS_OFF + (size_t)(c*NN + I)*NN + J] = acc;
    } else if (blk < NKS + 3) {
        int wv = t >> 6, l = t & 63;
        int cb = (blk - NKS)*4 + wv;
        if (cb < NC) {
            float* A  = sh + wv*304;
            float* V  = A + 144;
            float* rc = A + 288;
            float* rs = A + 294;
            for (int u = l; u < 144; u += 64) {
                int i = u / 12, j = u % 12;
                int kmax = (i < j) ? i : j;
                const float* a = Lt + cb*144 + i*12;
                const float* b = Lt + cb*144 + j*12;
                float s = 0.f;
                for (int k = 0; k <= kmax; ++k) s += a[k]*b[k];
                A[u] = s; V[u] = (i == j) ? 1.f : 0.f;
            }
            WB();
            for (int sweep = 0; sweep < 5; ++sweep)
            for (int r = 0; r < 11; ++r) {
                if (l < 6) {
                    int p, q; jpair(r, l, p, q);
                    float app = A[p*13], aqq = A[q*13], apq = A[p*12 + q];
                    float cs = 1.f, sn = 0.f;
                    if (fabsf(apq) > 1e-30f) {
                        float tau = (aqq - app) / (2.f * apq);
                        float t2 = ((tau >= 0.f) ? 1.f : -1.f) / (fabsf(tau) + sqrtf(1.f + tau*tau));
                        cs = 1.f / sqrtf(1.f + t2*t2);
                        sn = t2 * cs;
                    }
                    rc[l] = cs; rs[l] = sn;
                }
                WB();
                for (int u = l; u < 72; u += 64) {
                    int pi = u / 12, k = u % 12, p, q;
                    jpair(r, pi, p, q);
                    float cs = rc[pi], sn = rs[pi];
                    float x = A[p*12 + k], y = A[q*12 + k];
                    A[p*12 + k] = cs*x - sn*y;
                    A[q*12 + k] = sn*x + cs*y;
                }
                WB();
                for (int u = l; u < 144; u += 64) {
                    int isV = (u >= 72);
                    int v2 = isV ? u - 72 : u;
                    int pi = v2 / 12, i = v2 % 12, p, q;
                    jpair(r, pi, p, q);
                    float cs = rc[pi], sn = rs[pi];
                    float* M = isV ? V : A;
                    float x = M[i*12 + p], y = M[i*12 + q];
                    M[i*12 + p] = cs*x - sn*y;
                    M[i*12 + q] = sn*x + cs*y;
                }
                WB();
            }
            if (l < 12) ws[DT_OFF + cb*12 + l] = A[l*13];
            for (int u = l; u < 144; u += 64) ws[UT_OFF + cb*144 + u] = V[u];
            float su = 0.f;
            for (int i = l; i < NN; i += 64) su += logf(Ls[(size_t)(cb*NN + i)*NN + i]);
            for (int o = 32; o; o >>= 1) su += __shfl_down(su, o, 64);
            if (l == 0) ws[ULOG_OFF + cb] = su;
            float sv = (l < 12) ? logf(Lt[cb*144 + l*13]) : 0.f;
            for (int o = 32; o; o >>= 1) sv += __shfl_down(sv, o, 64);
            if (l == 0) ws[VLOG_OFF + cb] = sv;
        }
        if (blk == NKS && t == 0) *((int*)(ws + CNT_OFF)) = 0;
    } else {
        int mb = blk - (NKS + 3);
        int base = mb * 2484;
        float mk = 0.f, dd = 0.f;
        for (int u = base + t; u < base + 2484; u += 256) {
            float m2 = (uns[u] != 0.f) ? 1.f : 0.f;
            mk += m2;
            dd += fabsf(mu[u] - tg[u]) * m2;
        }
        for (int o = 32; o; o >>= 1) {
            mk += __shfl_down(mk, o, 64);
            dd += __shfl_down(dd, o, 64);
        }
        int wv = t >> 6, l = t & 63;
        if (l == 0) { sh[wv] = mk; sh[16 + wv] = dd; }
        __syncthreads();
        if (t == 0) {
            float a = 0.f, b2 = 0.f;
            for (int q = 0; q < 4; ++q) { a += sh[q]; b2 += sh[16 + q]; }
            ws[MAEC_OFF + mb] = a;
            ws[MAEA_OFF + mb] = b2;
        }
    }
}

// kD R12: R11's 32-wide-panel skeleton (2 barriers/panel) with the register
// diet that R11 lacked: solve32 runs as lo16-solve / L21-apply / hi16-solve
// (max ~48 live regs vs arow[32]+lr[32] ~64+ that spilled 182 MB), and ldg
// stride 36 (R11's stride-32 diag stores were 32-way bank conflicts).
__global__ __launch_bounds__(KDT)
void kD(const float* __restrict__ sig,
        const float* __restrict__ mu,
        const float* __restrict__ tg,
        const float* __restrict__ wgt,
        float* __restrict__ ws,
        float* __restrict__ out) {
    extern __shared__ float lds[];
    float* Apk = lds;                    // 22048
    float* W   = Apk + TRIP;             // 6784
    float* Pt  = W + WR*WST;             // 32*244 = 7808
    float* ldg = Pt + 32*PTS;            // 32*36 = 1152
    float* dnv = ldg + 32*LST;           // 32
    float* utl = dnv + 32;               // 12
    __shared__ int lflag;
    int t = threadIdx.x;
    int bid = blockIdx.x;
    int cj = bid >> 1, hf = bid & 1;
    int c = cj / TT, jj = cj % TT;
    float dt = ws[DT_OFF + cj];
    float sg = sig[c], sg2 = sg*sg;
    const float* KsC = ws + KS_OFF + (size_t)c*NN*NN;

    if (t < 12) utl[t] = ws[UT_OFF + c*144 + t*12 + jj];
    for (int f = t; f < QTOT; f += KDT) {
        int r = (int)((sqrtf(32.f*(float)f + 25.f) - 5.f)*0.5f);
        while ((roff(r+1) >> 2) <= f) ++r;
        while ((roff(r) >> 2) > f) --r;
        int c4 = (f - (roff(r) >> 2)) << 2;
        float4 v;
        float* ve = (float*)&v;
        #pragma unroll
        for (int e = 0; e < 4; ++e) {
            int cc = c4 + e;
            float x;
            if (r == NN) x = (cc == NN) ? 1.f : 0.f;
            else if (cc > r) x = 0.f;
            else { x = dt * KsC[r*NN + cc]; if (cc == r) x += sg2; }
            ve[e] = x;
        }
        *(float4*)(Apk + roff(r) + c4) = v;
    }
    __syncthreads();
    for (int u = t; u < WR*NN; u += KDT) {
        int wb2 = u / NN, i = u - wb2*NN;
        int b = hf*WR + wb2;
        const float4* mp = (const float4*)(mu + (size_t)(b*NN + i)*TT);
        const float4* tp = (const float4*)(tg + (size_t)(b*NN + i)*TT);
        float4 m0 = mp[0], m1 = mp[1], m2 = mp[2];
        float4 t0 = tp[0], t1 = tp[1], t2 = tp[2];
        float s = (t0.x-m0.x)*utl[0] + (t0.y-m0.y)*utl[1] + (t0.z-m0.z)*utl[2]
                + (t0.w-m0.w)*utl[3] + (t1.x-m1.x)*utl[4] + (t1.y-m1.y)*utl[5]
                + (t1.z-m1.z)*utl[6] + (t1.w-m1.w)*utl[7] + (t2.x-m2.x)*utl[8]
                + (t2.y-m2.y)*utl[9] + (t2.z-m2.z)*utl[10] + (t2.w-m2.w)*utl[11];
        W[wb2*WST + i] = s;
    }
    if (t < WR) W[t*WST + NN] = 0.f;
    __syncthreads();

    int wb = t - 192;
    bool isWth = (t >= 192 && t < 224);

    auto diagf32 = [&](int kd0) {        // wave0, lane r holds row r
        int r = t;
        int rr = (r < 32) ? (kd0 + r) : kd0;
        int base = roff(rr) + kd0;
        float a[32];
        #pragma unroll
        for (int m4 = 0; m4 < 8; ++m4)
            *(float4*)(a + 4*m4) = *(const float4*)(Apk + base + 4*m4);
        #pragma unroll
        for (int kk = 0; kk < 32; ++kk) {
            float d = __shfl(a[kk], kk);
            float dv = 1.0f / sqrtf(d);
            if (t == 0) dnv[kk] = dv;
            if (r < 32 && r > kk) a[kk] *= dv;
            #pragma unroll
            for (int j2 = kk+1; j2 < 32; ++j2) {
                float v = __shfl(a[kk], j2);
                if (r < 32 && r > kk && j2 <= r) a[j2] -= a[kk]*v;
            }
        }
        if (r < 32) {
            #pragma unroll
            for (int m = 0; m < 32; ++m) ldg[r*LST + m] = a[m];
        }
    };
    auto diagf16 = [&](int kd0) {
        int r = t;
        int rr = (r < 16) ? (kd0 + r) : kd0;
        int base = roff(rr) + kd0;
        float a[16];
        #pragma unroll
        for (int m4 = 0; m4 < 4; ++m4)
            *(float4*)(a + 4*m4) = *(const float4*)(Apk + base + 4*m4);
        #pragma unroll
        for (int kk = 0; kk < 16; ++kk) {
            float d = __shfl(a[kk], kk);
            float dv = 1.0f / sqrtf(d);
            if (t == 0) dnv[kk] = dv;
            if (r < 16 && r > kk) a[kk] *= dv;
            #pragma unroll
            for (int j2 = kk+1; j2 < 16; ++j2) {
                float v = __shfl(a[kk], j2);
                if (r < 16 && r > kk && j2 <= r) a[j2] -= a[kk]*v;
            }
        }
        if (r < 16) {
            #pragma unroll
            for (int m = 0; m < 16; ++m) ldg[r*LST + m] = a[m];
        }
    };
    auto tileu = [&](int rbase, int cbase) {   // rank-32 4x4 tile
        float4 acc0 = make_float4(0.f,0.f,0.f,0.f);
        float4 acc1 = acc0, acc2 = acc0, acc3 = acc0;
        #pragma unroll
        for (int kk = 0; kk < 32; ++kk) {
            const float* pr = Pt + kk*PTS;
            float4 a0 = *(const float4*)(pr + rbase);
            float4 bv = *(const float4*)(pr + cbase);
            acc0.x += a0.x*bv.x; acc0.y += a0.x*bv.y; acc0.z += a0.x*bv.z; acc0.w += a0.x*bv.w;
            acc1.x += a0.y*bv.x; acc1.y += a0.y*bv.y; acc1.z += a0.y*bv.z; acc1.w += a0.y*bv.w;
            acc2.x += a0.z*bv.x; acc2.y += a0.z*bv.y; acc2.z += a0.z*bv.z; acc2.w += a0.z*bv.w;
            acc3.x += a0.w*bv.x; acc3.y += a0.w*bv.y; acc3.z += a0.w*bv.z; acc3.w += a0.w*bv.w;
        }
        float4 accs[4] = {acc0, acc1, acc2, acc3};
        int ro = roff(rbase);
        #pragma unroll
        for (int ri = 0; ri < 4; ++ri) {
            int rho = rbase + ri;
            if (rho >= NP) {
                float* wp = W + (rho - NP)*WST + cbase;
                float4 w = *(float4*)wp;
                w.x -= accs[ri].x; w.y -= accs[ri].y; w.z -= accs[ri].z; w.w -= accs[ri].w;
                *(float4*)wp = w;
            } else if (cbase + 3 <= rho) {
                float* ap = Apk + ro + cbase;
                float4 w = *(float4*)ap;
                w.x -= accs[ri].x; w.y -= accs[ri].y; w.z -= accs[ri].z; w.w -= accs[ri].w;
                *(float4*)ap = w;
            } else if (cbase <= rho) {
                float* ap = Apk + ro;
                const float* af = (const float*)&accs[ri];
                #pragma unroll
                for (int e = 0; e < 4; ++e) {
                    int jc = cbase + e;
                    if (jc <= rho) ap[jc] -= af[e];
                }
            }
            ro += (rho + 4) & ~3;
        }
    };

    if (t < 64) diagf32(0);
    __syncthreads();

    float zacc = 0.f;
    for (int p = 0; p < 6; ++p) {
        int k0 = 32*p, k1 = k0 + 32;
        int nA = NP - k1;
        bool isA = (t < nA);
        // ---- solve(p), pw=32, two-stage (register diet)
        if (isA || isWth) {
            float lo[16], hi[16];
            if (isA) {
                int ab = roff(k1 + t) + k0;
                #pragma unroll
                for (int m4 = 0; m4 < 4; ++m4)
                    *(float4*)(lo + 4*m4) = *(const float4*)(Apk + ab + 4*m4);
                #pragma unroll
                for (int m4 = 0; m4 < 4; ++m4)
                    *(float4*)(hi + 4*m4) = *(const float4*)(Apk + ab + 16 + 4*m4);
            } else {
                int wbse = wb*WST + k0;
                #pragma unroll
                for (int m4 = 0; m4 < 4; ++m4)
                    *(float4*)(lo + 4*m4) = *(const float4*)(W + wbse + 4*m4);
                #pragma unroll
                for (int m4 = 0; m4 < 4; ++m4)
                    *(float4*)(hi + 4*m4) = *(const float4*)(W + wbse + 16 + 4*m4);
            }
            // stage 1: solve lo with triangle rows 0..15
            #pragma unroll
            for (int kk = 0; kk < 16; ++kk) {
                float lr[16];
                #pragma unroll
                for (int m4 = 0; m4 <= (kk >> 2); ++m4)
                    *(float4*)(lr + 4*m4) = *(const float4*)(ldg + kk*LST + 4*m4);
                float x = lo[kk];
                #pragma unroll
                for (int m = 0; m < kk; ++m) x -= lo[m]*lr[m];
                lo[kk] = x * dnv[kk];
            }
            // stage 2: hi -= L[16..31][0..15] * lo
            #pragma unroll
            for (int kk = 0; kk < 16; ++kk) {
                float lr[16];
                #pragma unroll
                for (int m4 = 0; m4 < 4; ++m4)
                    *(float4*)(lr + 4*m4) = *(const float4*)(ldg + (16+kk)*LST + 4*m4);
                float x = hi[kk];
                #pragma unroll
                for (int m = 0; m < 16; ++m) x -= lo[m]*lr[m];
                hi[kk] = x;
            }
            // stage 3: solve hi with triangle rows 16..31 (cols 16..31)
            #pragma unroll
            for (int kk = 0; kk < 16; ++kk) {
                float lr[16];
                #pragma unroll
                for (int m4 = 0; m4 <= (kk >> 2); ++m4)
                    *(float4*)(lr + 4*m4) = *(const float4*)(ldg + (16+kk)*LST + 16 + 4*m4);
                float x = hi[kk];
                #pragma unroll
                for (int m = 0; m < kk; ++m) x -= hi[m]*lr[m];
                hi[kk] = x * dnv[16 + kk];
            }
            int rho = isWth ? (NP + wb) : (k1 + t);
            if (isWth) {
                #pragma unroll
                for (int m = 0; m < 16; ++m) zacc += lo[m]*lo[m] + hi[m]*hi[m];
            }
            #pragma unroll
            for (int m = 0; m < 16; ++m) {
                Pt[m*PTS + rho] = lo[m];
                Pt[(16+m)*PTS + rho] = hi[m];
            }
        }
        __syncthreads();
        // ---- merged update phase
        if (t < 64) {
            int rb = t >> 3, cb = t & 7;
            int rbase = k1 + 4*rb, cbase = k1 + 4*cb;
            if (rbase < NP && cbase < NP && !(rbase + 3 < cbase))
                tileu(rbase, cbase);
            WB();   // same-wave DS ordering: tiles before diag reads
            if (p < 5) diagf32(k1); else diagf16(k1);
        } else {
            int nrb = (240 - k1) >> 2, ncb = (NP - k1) >> 2;
            int nslots = nrb * ncb;
            for (int e = t - 64; e < nslots; e += 448) {
                int rb = e / ncb, cb = e - rb*ncb;
                int rbase = k1 + 4*rb, cbase = k1 + 4*cb;
                if (rbase + 3 < cbase) continue;
                if (rbase < k1 + 32 && cbase < k1 + 32 && rbase < NP)
                    continue;
                tileu(rbase, cbase);
            }
        }
        __syncthreads();
    }
    // ---- final 16-wide panel: W rows only
    if (isWth) {
        float arow[16];
        int wbse = wb*WST + 192;
        #pragma unroll
        for (int m4 = 0; m4 < 4; ++m4)
            *(float4*)(arow + 4*m4) = *(const float4*)(W + wbse + 4*m4);
        #pragma unroll
        for (int kk = 0; kk < 16; ++kk) {
            float lr[16];
            #pragma unroll
            for (int m4 = 0; m4 <= (kk >> 2); ++m4)
                *(float4*)(lr + 4*m4) = *(const float4*)(ldg + kk*LST + 4*m4);
            float x = arow[kk];
            #pragma unroll
            for (int m = 0; m < kk; ++m) x -= arow[m]*lr[m];
            arow[kk] = x * dnv[kk];
        }
        #pragma unroll
        for (int m = 0; m < 16; ++m) zacc += arow[m]*arow[m];
        ws[SSQ_OFF + (cj << 6) + hf*WR + wb] = zacc;
    }
    // last-block epilogue
    __threadfence();
    __syncthreads();
    if (t == 0) {
        int old = atomicAdd((int*)(ws + CNT_OFF), 1);
        lflag = (old == NBLK - 1) ? 1 : 0;
    }
    __syncthreads();
    if (!lflag) return;
    __threadfence();
    float* ep = Apk;
    float* nl = Apk + 640;
    const float C0 = -0.5f * 2484.0f * 1.8378770664093453f;
    for (int u = t; u < 640; u += KDT) {
        int b2 = u / NC, cc = u % NC;
        float q = 0.f;
        for (int j2 = 0; j2 < TT; ++j2) q += ws[SSQ_OFF + (cc*TT + j2)*64 + b2];
        ep[u] = C0 - 0.5f*q + 207.f*ws[VLOG_OFF + cc] + 12.f*ws[ULOG_OFF + cc]
                + logf(wgt[b2*NC + cc]);
    }
    __syncthreads();
    if (t < 64) {
        float mx = -1e30f;
        for (int cc = 0; cc < NC; ++cc) mx = fmaxf(mx, ep[t*NC + cc]);
        float s = 0.f;
        for (int cc = 0; cc < NC; ++cc) s += expf(ep[t*NC + cc] - mx);
        nl[t] = -(mx + logf(s));
    }
    __syncthreads();
    if (t < 64) {
        float v = nl[t];
        for (int o = 32; o; o >>= 1) v += __shfl_down(v, o, 64);
        if (t == 0) {
            float sm = 0.f, sa = 0.f;
            for (int q2 = 0; q2 < 64; ++q2) {
                sm += ws[MAEC_OFF + q2];
                sa += ws[MAEA_OFF + q2];
            }
            float mse = (sm > 0.f) ? sa / sm : 0.f;
            out[0] = 0.1f * (v * (1.f/64.f)) + 0.9f * mse;
        }
    }
}

extern "C" void kernel_launch(void* const* d_in, const int* in_sizes, int n_in,
                              void* d_out, int out_size, void* d_ws, size_t ws_size,
                              hipStream_t stream) {
    const float* mu  = (const float*)d_in[0];
    const float* tg  = (const float*)d_in[1];
    const float* uns = (const float*)d_in[2];
    const float* wgt = (const float*)d_in[3];
    const float* sig = (const float*)d_in[4];
    const float* Ls  = (const float*)d_in[6];
    const float* Lt  = (const float*)d_in[7];
    float* out = (float*)d_out;
    float* ws  = (float*)d_ws;

    const int kd_lds = (TRIP + WR*WST + 32*PTS + 32*LST + 32 + 12) * 4; // 151,344 B
    (void)hipFuncSetAttribute((const void*)kD,
                              hipFuncAttributeMaxDynamicSharedMemorySize, kd_lds);

    k1<<<NKS + 3 + 64, 256, 0, stream>>>(Ls, Lt, mu, tg, uns, ws);
    kD<<<NBLK, KDT, kd_lds, stream>>>(sig, mu, tg, wgt, ws, out);
}

// Round 13
// 453.111 us; speedup vs baseline: 1.0058x; 1.0058x over previous
//
#include <hip/hip_runtime.h>
#include <math.h>

#define BB 64
#define NN 207
#define TT 12
#define NC 10
#define NP 208              // padded matrix dim (pad row 207: identity)
#define TRIP 22048          // 4-aligned packed lower triangle
#define QTOT 5512           // TRIP/4 quad-chunks for staging
#define WR 32               // RHS rows per block
#define WST 212             // W row stride
#define PTS 244             // Pt row stride (rho max 239)
#define LST 36              // ldg row stride (f4-aligned, non-pow2)
#define KDT 512
#define NBLK 240
#define NKS 910             // k1 Ks tile blocks

// ws layout (float offsets).
#define KS_OFF   0          // [C][N][N]       428490
#define DT_OFF   428490     // [C][T]          120
#define UT_OFF   428610     // [C][T][T]       1440
#define ULOG_OFF 430050
#define VLOG_OFF 430060
#define CNT_OFF  430070
#define MAEC_OFF 430071
#define MAEA_OFF 430135
#define SSQ_OFF  430199     // [C][T][B]       7680

__device__ __forceinline__ int roff(int r) {
    return ((r*(r+1)) >> 1) + 6*(r >> 2) + ((0x6530 >> ((r & 3) << 2)) & 15);
}

__device__ __forceinline__ void WB() {
    __builtin_amdgcn_wave_barrier();
    __asm__ volatile("" ::: "memory");
}

__device__ inline void jpair(int r, int pi, int& p, int& q) {
    if (pi == 0) { p = 11; q = r % 11; }
    else { p = (r + pi) % 11; q = (r + 11 - pi) % 11; }
}

// k1: unchanged (Ks tiles + Jacobi + MAE partials)
__global__ __launch_bounds__(256) void k1(const float* __restrict__ Ls,
                                          const float* __restrict__ Lt,
                                          const float* __restrict__ mu,
                                          const float* __restrict__ tg,
                                          const float* __restrict__ uns,
                                          float* __restrict__ ws) {
    __shared__ float sh[1216];
    int t = threadIdx.x;
    int blk = blockIdx.x;
    if (blk < NKS) {
        int c = blk / 91, r = blk % 91;
        int it = (int)((sqrtf(8.f*r + 1.f) - 1.f)*0.5f);
        while ((it+1)*(it+2)/2 <= r) ++it;
        while (it*(it+1)/2 > r) --it;
        int jt = r - it*(it+1)/2;
        int I0 = it*16, J0 = jt*16;
        float* As = sh;
        float* Bs = sh + 272;
        int ti = t >> 4, tj = t & 15;
        int srow = t >> 4, skk = t & 15;
        float acc = 0.f;
        for (int kc = 0; kc <= jt; ++kc) {
            int k = kc*16 + skk;
            int ia = I0 + srow, jb = J0 + srow;
            As[srow*17 + skk] = (ia < NN && k < NN) ? Ls[(size_t)(c*NN + ia)*NN + k] : 0.f;
            Bs[srow*17 + skk] = (jb < NN && k < NN) ? Ls[(size_t)(c*NN + jb)*NN + k] : 0.f;
            __syncthreads();
            #pragma unroll
            for (int kk = 0; kk < 16; ++kk)
                acc += As[ti*17 + kk] * Bs[tj*17 + kk];
            __syncthreads();
        }
        int I = I0 + ti, J = J0 + tj;
        if (I < NN && J < NN)
            ws[KS_OFF + (size_t)(c*NN + I)*NN + J] = acc;
    } else if (blk < NKS + 3) {
        int wv = t >> 6, l = t & 63;
        int cb = (blk - NKS)*4 + wv;
        if (cb < NC) {
            float* A  = sh + wv*304;
            float* V  = A + 144;
            float* rc = A + 288;
            float* rs = A + 294;
            for (int u = l; u < 144; u += 64) {
                int i = u / 12, j = u % 12;
                int kmax = (i < j) ? i : j;
                const float* a = Lt + cb*144 + i*12;
                const float* b = Lt + cb*144 + j*12;
                float s = 0.f;
                for (int k = 0; k <= kmax; ++k) s += a[k]*b[k];
                A[u] = s; V[u] = (i == j) ? 1.f : 0.f;
            }
            WB();
            for (int sweep = 0; sweep < 5; ++sweep)
            for (int r = 0; r < 11; ++r) {
                if (l < 6) {
                    int p, q; jpair(r, l, p, q);
                    float app = A[p*13], aqq = A[q*13], apq = A[p*12 + q];
                    float cs = 1.f, sn = 0.f;
                    if (fabsf(apq) > 1e-30f) {
                        float tau = (aqq - app) / (2.f * apq);
                        float t2 = ((tau >= 0.f) ? 1.f : -1.f) / (fabsf(tau) + sqrtf(1.f + tau*tau));
                        cs = 1.f / sqrtf(1.f + t2*t2);
                        sn = t2 * cs;
                    }
                    rc[l] = cs; rs[l] = sn;
                }
                WB();
                for (int u = l; u < 72; u += 64) {
                    int pi = u / 12, k = u % 12, p, q;
                    jpair(r, pi, p, q);
                    float cs = rc[pi], sn = rs[pi];
                    float x = A[p*12 + k], y = A[q*12 + k];
                    A[p*12 + k] = cs*x - sn*y;
                    A[q*12 + k] = sn*x + cs*y;
                }
                WB();
                for (int u = l; u < 144; u += 64) {
                    int isV = (u >= 72);
                    int v2 = isV ? u - 72 : u;
                    int pi = v2 / 12, i = v2 % 12, p, q;
                    jpair(r, pi, p, q);
                    float cs = rc[pi], sn = rs[pi];
                    float* M = isV ? V : A;
                    float x = M[i*12 + p], y = M[i*12 + q];
                    M[i*12 + p] = cs*x - sn*y;
                    M[i*12 + q] = sn*x + cs*y;
                }
                WB();
            }
            if (l < 12) ws[DT_OFF + cb*12 + l] = A[l*13];
            for (int u = l; u < 144; u += 64) ws[UT_OFF + cb*144 + u] = V[u];
            float su = 0.f;
            for (int i = l; i < NN; i += 64) su += logf(Ls[(size_t)(cb*NN + i)*NN + i]);
            for (int o = 32; o; o >>= 1) su += __shfl_down(su, o, 64);
            if (l == 0) ws[ULOG_OFF + cb] = su;
            float sv = (l < 12) ? logf(Lt[cb*144 + l*13]) : 0.f;
            for (int o = 32; o; o >>= 1) sv += __shfl_down(sv, o, 64);
            if (l == 0) ws[VLOG_OFF + cb] = sv;
        }
        if (blk == NKS && t == 0) *((int*)(ws + CNT_OFF)) = 0;
    } else {
        int mb = blk - (NKS + 3);
        int base = mb * 2484;
        float mk = 0.f, dd = 0.f;
        for (int u = base + t; u < base + 2484; u += 256) {
            float m2 = (uns[u] != 0.f) ? 1.f : 0.f;
            mk += m2;
            dd += fabsf(mu[u] - tg[u]) * m2;
        }
        for (int o = 32; o; o >>= 1) {
            mk += __shfl_down(mk, o, 64);
            dd += __shfl_down(dd, o, 64);
        }
        int wv = t >> 6, l = t & 63;
        if (l == 0) { sh[wv] = mk; sh[16 + wv] = dd; }
        __syncthreads();
        if (t == 0) {
            float a = 0.f, b2 = 0.f;
            for (int q = 0; q < 4; ++q) { a += sh[q]; b2 += sh[16 + q]; }
            ws[MAEC_OFF + mb] = a;
            ws[MAEA_OFF + mb] = b2;
        }
    }
}

// kD R13: 32-panel skeleton, spiller fixed. R11/R12 WRITE_SIZE was identical
// (182 MB) across a full solve restructure -> diagf32's a[32] was the spill
// source, not the solve. New diagf32: 2 lanes/row (lane l: row l&31 cols 0-15;
// lane l+32: cols 16-31), x[16] per lane, 64-lane shfl broadcasts from the
// half owning column kk. Solve keeps R12 two-stage + WB hoist-caps every 2 kk
// (stage2 iterations are independent -> unbounded lr hoisting otherwise).
__global__ __launch_bounds__(KDT)
void kD(const float* __restrict__ sig,
        const float* __restrict__ mu,
        const float* __restrict__ tg,
        const float* __restrict__ wgt,
        float* __restrict__ ws,
        float* __restrict__ out) {
    extern __shared__ float lds[];
    float* Apk = lds;                    // 22048
    float* W   = Apk + TRIP;             // 6784
    float* Pt  = W + WR*WST;             // 7808
    float* ldg = Pt + 32*PTS;            // 32*36 = 1152
    float* dnv = ldg + 32*LST;           // 32
    float* utl = dnv + 32;               // 12
    __shared__ int lflag;
    int t = threadIdx.x;
    int bid = blockIdx.x;
    int cj = bid >> 1, hf = bid & 1;
    int c = cj / TT, jj = cj % TT;
    float dt = ws[DT_OFF + cj];
    float sg = sig[c], sg2 = sg*sg;
    const float* KsC = ws + KS_OFF + (size_t)c*NN*NN;

    if (t < 12) utl[t] = ws[UT_OFF + c*144 + t*12 + jj];
    for (int f = t; f < QTOT; f += KDT) {
        int r = (int)((sqrtf(32.f*(float)f + 25.f) - 5.f)*0.5f);
        while ((roff(r+1) >> 2) <= f) ++r;
        while ((roff(r) >> 2) > f) --r;
        int c4 = (f - (roff(r) >> 2)) << 2;
        float4 v;
        float* ve = (float*)&v;
        #pragma unroll
        for (int e = 0; e < 4; ++e) {
            int cc = c4 + e;
            float x;
            if (r == NN) x = (cc == NN) ? 1.f : 0.f;
            else if (cc > r) x = 0.f;
            else { x = dt * KsC[r*NN + cc]; if (cc == r) x += sg2; }
            ve[e] = x;
        }
        *(float4*)(Apk + roff(r) + c4) = v;
    }
    __syncthreads();
    for (int u = t; u < WR*NN; u += KDT) {
        int wb2 = u / NN, i = u - wb2*NN;
        int b = hf*WR + wb2;
        const float4* mp = (const float4*)(mu + (size_t)(b*NN + i)*TT);
        const float4* tp = (const float4*)(tg + (size_t)(b*NN + i)*TT);
        float4 m0 = mp[0], m1 = mp[1], m2 = mp[2];
        float4 t0 = tp[0], t1 = tp[1], t2 = tp[2];
        float s = (t0.x-m0.x)*utl[0] + (t0.y-m0.y)*utl[1] + (t0.z-m0.z)*utl[2]
                + (t0.w-m0.w)*utl[3] + (t1.x-m1.x)*utl[4] + (t1.y-m1.y)*utl[5]
                + (t1.z-m1.z)*utl[6] + (t1.w-m1.w)*utl[7] + (t2.x-m2.x)*utl[8]
                + (t2.y-m2.y)*utl[9] + (t2.z-m2.z)*utl[10] + (t2.w-m2.w)*utl[11];
        W[wb2*WST + i] = s;
    }
    if (t < WR) W[t*WST + NN] = 0.f;
    __syncthreads();

    int wb = t - 192;
    bool isWth = (t >= 192 && t < 224);

    // split-row 32x32 diag Cholesky: 16 regs/lane (the R11/R12 spiller had 32)
    auto diagf32 = [&](int kd0) {        // wave0 (t<64): lane t, half h, row r
        int h = t >> 5, r = t & 31;
        int base = roff(kd0 + r) + kd0 + 16*h;
        float x[16];
        #pragma unroll
        for (int m4 = 0; m4 < 4; ++m4)
            *(float4*)(x + 4*m4) = *(const float4*)(Apk + base + 4*m4);
        #pragma unroll
        for (int kk = 0; kk < 32; ++kk) {
            const int hk = kk >> 4, ck = kk & 15;
            float d = __shfl(x[ck], kk + 32*hk, 64);     // pivot (unscaled)
            float dv = 1.0f / sqrtf(d);
            if (t == 0) dnv[kk] = dv;
            if (h == hk && r > kk) x[ck] *= dv;          // scale column kk
            float Lself = __shfl(x[ck], r + 32*hk, 64);  // L[r][kk] (valid r>kk)
            #pragma unroll
            for (int j2 = kk+1; j2 < 32; ++j2) {
                float v = __shfl(x[ck], j2 + 32*hk, 64); // L[j2][kk]
                if ((j2 >> 4) == h && j2 <= r) x[j2 & 15] -= Lself * v;
            }
        }
        #pragma unroll
        for (int m4 = 0; m4 < 4; ++m4)
            *(float4*)(ldg + r*LST + 16*h + 4*m4) = *(const float4*)(x + 4*m4);
    };
    auto diagf16 = [&](int kd0) {
        int r = t;
        int rr = (r < 16) ? (kd0 + r) : kd0;
        int base = roff(rr) + kd0;
        float a[16];
        #pragma unroll
        for (int m4 = 0; m4 < 4; ++m4)
            *(float4*)(a + 4*m4) = *(const float4*)(Apk + base + 4*m4);
        #pragma unroll
        for (int kk = 0; kk < 16; ++kk) {
            float d = __shfl(a[kk], kk);
            float dv = 1.0f / sqrtf(d);
            if (t == 0) dnv[kk] = dv;
            if (r < 16 && r > kk) a[kk] *= dv;
            #pragma unroll
            for (int j2 = kk+1; j2 < 16; ++j2) {
                float v = __shfl(a[kk], j2);
                if (r < 16 && r > kk && j2 <= r) a[j2] -= a[kk]*v;
            }
        }
        if (r < 16) {
            #pragma unroll
            for (int m = 0; m < 16; ++m) ldg[r*LST + m] = a[m];
        }
    };
    auto tileu = [&](int rbase, int cbase) {   // rank-32 4x4 tile
        float4 acc0 = make_float4(0.f,0.f,0.f,0.f);
        float4 acc1 = acc0, acc2 = acc0, acc3 = acc0;
        #pragma unroll
        for (int kk = 0; kk < 32; ++kk) {
            const float* pr = Pt + kk*PTS;
            float4 a0 = *(const float4*)(pr + rbase);
            float4 bv = *(const float4*)(pr + cbase);
            acc0.x += a0.x*bv.x; acc0.y += a0.x*bv.y; acc0.z += a0.x*bv.z; acc0.w += a0.x*bv.w;
            acc1.x += a0.y*bv.x; acc1.y += a0.y*bv.y; acc1.z += a0.y*bv.z; acc1.w += a0.y*bv.w;
            acc2.x += a0.z*bv.x; acc2.y += a0.z*bv.y; acc2.z += a0.z*bv.z; acc2.w += a0.z*bv.w;
            acc3.x += a0.w*bv.x; acc3.y += a0.w*bv.y; acc3.z += a0.w*bv.z; acc3.w += a0.w*bv.w;
        }
        float4 accs[4] = {acc0, acc1, acc2, acc3};
        int ro = roff(rbase);
        #pragma unroll
        for (int ri = 0; ri < 4; ++ri) {
            int rho = rbase + ri;
            if (rho >= NP) {
                float* wp = W + (rho - NP)*WST + cbase;
                float4 w = *(float4*)wp;
                w.x -= accs[ri].x; w.y -= accs[ri].y; w.z -= accs[ri].z; w.w -= accs[ri].w;
                *(float4*)wp = w;
            } else if (cbase + 3 <= rho) {
                float* ap = Apk + ro + cbase;
                float4 w = *(float4*)ap;
                w.x -= accs[ri].x; w.y -= accs[ri].y; w.z -= accs[ri].z; w.w -= accs[ri].w;
                *(float4*)ap = w;
            } else if (cbase <= rho) {
                float* ap = Apk + ro;
                const float* af = (const float*)&accs[ri];
                #pragma unroll
                for (int e = 0; e < 4; ++e) {
                    int jc = cbase + e;
                    if (jc <= rho) ap[jc] -= af[e];
                }
            }
            ro += (rho + 4) & ~3;
        }
    };

    if (t < 64) diagf32(0);
    __syncthreads();

    float zacc = 0.f;
    for (int p = 0; p < 6; ++p) {
        int k0 = 32*p, k1 = k0 + 32;
        int nA = NP - k1;
        bool isA = (t < nA);
        // ---- solve(p), pw=32, two-stage + WB hoist caps
        if (isA || isWth) {
            float lo[16], hi[16];
            if (isA) {
                int ab = roff(k1 + t) + k0;
                #pragma unroll
                for (int m4 = 0; m4 < 4; ++m4)
                    *(float4*)(lo + 4*m4) = *(const float4*)(Apk + ab + 4*m4);
                #pragma unroll
                for (int m4 = 0; m4 < 4; ++m4)
                    *(float4*)(hi + 4*m4) = *(const float4*)(Apk + ab + 16 + 4*m4);
            } else {
                int wbse = wb*WST + k0;
                #pragma unroll
                for (int m4 = 0; m4 < 4; ++m4)
                    *(float4*)(lo + 4*m4) = *(const float4*)(W + wbse + 4*m4);
                #pragma unroll
                for (int m4 = 0; m4 < 4; ++m4)
                    *(float4*)(hi + 4*m4) = *(const float4*)(W + wbse + 16 + 4*m4);
            }
            // stage 1: solve lo with triangle rows 0..15
            #pragma unroll
            for (int kk = 0; kk < 16; ++kk) {
                float lr[16];
                #pragma unroll
                for (int m4 = 0; m4 <= (kk >> 2); ++m4)
                    *(float4*)(lr + 4*m4) = *(const float4*)(ldg + kk*LST + 4*m4);
                float x = lo[kk];
                #pragma unroll
                for (int m = 0; m < kk; ++m) x -= lo[m]*lr[m];
                lo[kk] = x * dnv[kk];
                if ((kk & 1) == 1) WB();
            }
            // stage 2: hi -= L[16..31][0..15] * lo (independent iters: cap hoist)
            #pragma unroll
            for (int kk = 0; kk < 16; ++kk) {
                float lr[16];
                #pragma unroll
                for (int m4 = 0; m4 < 4; ++m4)
                    *(float4*)(lr + 4*m4) = *(const float4*)(ldg + (16+kk)*LST + 4*m4);
                float x = hi[kk];
                #pragma unroll
                for (int m = 0; m < 16; ++m) x -= lo[m]*lr[m];
                hi[kk] = x;
                if ((kk & 1) == 1) WB();
            }
            // stage 3: solve hi with triangle rows 16..31 (cols 16..31)
            #pragma unroll
            for (int kk = 0; kk < 16; ++kk) {
                float lr[16];
                #pragma unroll
                for (int m4 = 0; m4 <= (kk >> 2); ++m4)
                    *(float4*)(lr + 4*m4) = *(const float4*)(ldg + (16+kk)*LST + 16 + 4*m4);
                float x = hi[kk];
                #pragma unroll
                for (int m = 0; m < kk; ++m) x -= hi[m]*lr[m];
                hi[kk] = x * dnv[16 + kk];
                if ((kk & 1) == 1) WB();
            }
            int rho = isWth ? (NP + wb) : (k1 + t);
            if (isWth) {
                #pragma unroll
                for (int m = 0; m < 16; ++m) zacc += lo[m]*lo[m] + hi[m]*hi[m];
            }
            #pragma unroll
            for (int m = 0; m < 16; ++m) {
                Pt[m*PTS + rho] = lo[m];
                Pt[(16+m)*PTS + rho] = hi[m];
            }
        }
        __syncthreads();
        // ---- merged update phase
        if (t < 64) {
            int rb = t >> 3, cb = t & 7;
            int rbase = k1 + 4*rb, cbase = k1 + 4*cb;
            if (rbase < NP && cbase < NP && !(rbase + 3 < cbase))
                tileu(rbase, cbase);
            WB();   // same-wave DS ordering: tiles before diag reads
            if (p < 5) diagf32(k1); else diagf16(k1);
        } else {
            int nrb = (240 - k1) >> 2, ncb = (NP - k1) >> 2;
            int nslots = nrb * ncb;
            for (int e = t - 64; e < nslots; e += 448) {
                int rb = e / ncb, cb = e - rb*ncb;
                int rbase = k1 + 4*rb, cbase = k1 + 4*cb;
                if (rbase + 3 < cbase) continue;
                if (rbase < k1 + 32 && cbase < k1 + 32 && rbase < NP)
                    continue;
                tileu(rbase, cbase);
            }
        }
        __syncthreads();
    }
    // ---- final 16-wide panel: W rows only
    if (isWth) {
        float arow[16];
        int wbse = wb*WST + 192;
        #pragma unroll
        for (int m4 = 0; m4 < 4; ++m4)
            *(float4*)(arow + 4*m4) = *(const float4*)(W + wbse + 4*m4);
        #pragma unroll
        for (int kk = 0; kk < 16; ++kk) {
            float lr[16];
            #pragma unroll
            for (int m4 = 0; m4 <= (kk >> 2); ++m4)
                *(float4*)(lr + 4*m4) = *(const float4*)(ldg + kk*LST + 4*m4);
            float x = arow[kk];
            #pragma unroll
            for (int m = 0; m < kk; ++m) x -= arow[m]*lr[m];
            arow[kk] = x * dnv[kk];
            if ((kk & 1) == 1) WB();
        }
        #pragma unroll
        for (int m = 0; m < 16; ++m) zacc += arow[m]*arow[m];
        ws[SSQ_OFF + (cj << 6) + hf*WR + wb] = zacc;
    }
    // last-block epilogue
    __threadfence();
    __syncthreads();
    if (t == 0) {
        int old = atomicAdd((int*)(ws + CNT_OFF), 1);
        lflag = (old == NBLK - 1) ? 1 : 0;
    }
    __syncthreads();
    if (!lflag) return;
    __threadfence();
    float* ep = Apk;
    float* nl = Apk + 640;
    const float C0 = -0.5f * 2484.0f * 1.8378770664093453f;
    for (int u = t; u < 640; u += KDT) {
        int b2 = u / NC, cc = u % NC;
        float q = 0.f;
        for (int j2 = 0; j2 < TT; ++j2) q += ws[SSQ_OFF + (cc*TT + j2)*64 + b2];
        ep[u] = C0 - 0.5f*q + 207.f*ws[VLOG_OFF + cc] + 12.f*ws[ULOG_OFF + cc]
                + logf(wgt[b2*NC + cc]);
    }
    __syncthreads();
    if (t < 64) {
        float mx = -1e30f;
        for (int cc = 0; cc < NC; ++cc) mx = fmaxf(mx, ep[t*NC + cc]);
        float s = 0.f;
        for (int cc = 0; cc < NC; ++cc) s += expf(ep[t*NC + cc] - mx);
        nl[t] = -(mx + logf(s));
    }
    __syncthreads();
    if (t < 64) {
        float v = nl[t];
        for (int o = 32; o; o >>= 1) v += __shfl_down(v, o, 64);
        if (t == 0) {
            float sm = 0.f, sa = 0.f;
            for (int q2 = 0; q2 < 64; ++q2) {
                sm += ws[MAEC_OFF + q2];
                sa += ws[MAEA_OFF + q2];
            }
            float mse = (sm > 0.f) ? sa / sm : 0.f;
            out[0] = 0.1f * (v * (1.f/64.f)) + 0.9f * mse;
        }
    }
}

extern "C" void kernel_launch(void* const* d_in, const int* in_sizes, int n_in,
                              void* d_out, int out_size, void* d_ws, size_t ws_size,
                              hipStream_t stream) {
    const float* mu  = (const float*)d_in[0];
    const float* tg  = (const float*)d_in[1];
    const float* uns = (const float*)d_in[2];
    const float* wgt = (const float*)d_in[3];
    const float* sig = (const float*)d_in[4];
    const float* Ls  = (const float*)d_in[6];
    const float* Lt  = (const float*)d_in[7];
    float* out = (float*)d_out;
    float* ws  = (float*)d_ws;

    const int kd_lds = (TRIP + WR*WST + 32*PTS + 32*LST + 32 + 12) * 4; // 151,344 B
    (void)hipFuncSetAttribute((const void*)kD,
                              hipFuncAttributeMaxDynamicSharedMemorySize, kd_lds);

    k1<<<NKS + 3 + 64, 256, 0, stream>>>(Ls, Lt, mu, tg, uns, ws);
    kD<<<NBLK, KDT, kd_lds, stream>>>(sig, mu, tg, wgt, ws, out);
}

// Round 14
// 407.590 us; speedup vs baseline: 1.1181x; 1.1117x over previous
//
#include <hip/hip_runtime.h>
#include <math.h>

// R14 = exact revert to R10 (best measured: 403 us total, kD 264 us, no spill).
// 32-wide-panel line (R11-R13) closed per pre-committed exit: WRITE_SIZE stayed
// ~200 MB (VGPR 128 => scratch spill) through independent solve & diag diets;
// remaining suspect is the rank-32 tileu's fully-unrolled kk-loop hoisting
// ~64 f4 loads. If ever retried: bound the unroll (split 2x16 with sched
// fences), verify WRITE_SIZE < 1 MB before anything else.

#define BB 64
#define NN 207
#define TT 12
#define NC 10
#define NP 208              // padded matrix dim (pad row 207: identity)
#define TRIP 22048          // 4-aligned packed lower triangle
#define QTOT 5512           // TRIP/4 quad-chunks for staging
#define WR 32               // RHS rows per block
#define WST 212             // W row stride
#define PTS 244             // Pt row stride
#define KDT 512
#define NBLK 240
#define NKS 910             // k1 Ks tile blocks (10 comps x 91 lower tiles)

// ws layout (float offsets).
#define KS_OFF   0          // [C][N][N]       428490
#define DT_OFF   428490     // [C][T]          120
#define UT_OFF   428610     // [C][T][T]       1440
#define ULOG_OFF 430050
#define VLOG_OFF 430060
#define CNT_OFF  430070
#define MAEC_OFF 430071
#define MAEA_OFF 430135
#define SSQ_OFF  430199     // [C][T][B]       7680

__device__ __forceinline__ int roff(int r) {
    return ((r*(r+1)) >> 1) + 6*(r >> 2) + ((0x6530 >> ((r & 3) << 2)) & 15);
}

__device__ __forceinline__ void WB() {
    __builtin_amdgcn_wave_barrier();
    __asm__ volatile("" ::: "memory");
}

__device__ inline void jpair(int r, int pi, int& p, int& q) {
    if (pi == 0) { p = 11; q = r % 11; }
    else { p = (r + pi) % 11; q = (r + 11 - pi) % 11; }
}

// k1: blocks 0..909: Ks 16x16 output tiles via LDS-staged coalesced GEMM.
// Blocks 910..912: wave-parallel Jacobi (4 comps/block). 913..976: MAE partials.
__global__ __launch_bounds__(256) void k1(const float* __restrict__ Ls,
                                          const float* __restrict__ Lt,
                                          const float* __restrict__ mu,
                                          const float* __restrict__ tg,
                                          const float* __restrict__ uns,
                                          float* __restrict__ ws) {
    __shared__ float sh[1216];
    int t = threadIdx.x;
    int blk = blockIdx.x;
    if (blk < NKS) {
        int c = blk / 91, r = blk % 91;
        int it = (int)((sqrtf(8.f*r + 1.f) - 1.f)*0.5f);
        while ((it+1)*(it+2)/2 <= r) ++it;
        while (it*(it+1)/2 > r) --it;
        int jt = r - it*(it+1)/2;
        int I0 = it*16, J0 = jt*16;
        float* As = sh;
        float* Bs = sh + 272;
        int ti = t >> 4, tj = t & 15;
        int srow = t >> 4, skk = t & 15;
        float acc = 0.f;
        for (int kc = 0; kc <= jt; ++kc) {
            int k = kc*16 + skk;
            int ia = I0 + srow, jb = J0 + srow;
            As[srow*17 + skk] = (ia < NN && k < NN) ? Ls[(size_t)(c*NN + ia)*NN + k] : 0.f;
            Bs[srow*17 + skk] = (jb < NN && k < NN) ? Ls[(size_t)(c*NN + jb)*NN + k] : 0.f;
            __syncthreads();
            #pragma unroll
            for (int kk = 0; kk < 16; ++kk)
                acc += As[ti*17 + kk] * Bs[tj*17 + kk];
            __syncthreads();
        }
        int I = I0 + ti, J = J0 + tj;
        if (I < NN && J < NN)
            ws[KS_OFF + (size_t)(c*NN + I)*NN + J] = acc;
    } else if (blk < NKS + 3) {
        int wv = t >> 6, l = t & 63;
        int cb = (blk - NKS)*4 + wv;
        if (cb < NC) {
            float* A  = sh + wv*304;
            float* V  = A + 144;
            float* rc = A + 288;
            float* rs = A + 294;
            for (int u = l; u < 144; u += 64) {
                int i = u / 12, j = u % 12;
                int kmax = (i < j) ? i : j;
                const float* a = Lt + cb*144 + i*12;
                const float* b = Lt + cb*144 + j*12;
                float s = 0.f;
                for (int k = 0; k <= kmax; ++k) s += a[k]*b[k];
                A[u] = s; V[u] = (i == j) ? 1.f : 0.f;
            }
            WB();
            for (int sweep = 0; sweep < 5; ++sweep)
            for (int r = 0; r < 11; ++r) {
                if (l < 6) {
                    int p, q; jpair(r, l, p, q);
                    float app = A[p*13], aqq = A[q*13], apq = A[p*12 + q];
                    float cs = 1.f, sn = 0.f;
                    if (fabsf(apq) > 1e-30f) {
                        float tau = (aqq - app) / (2.f * apq);
                        float t2 = ((tau >= 0.f) ? 1.f : -1.f) / (fabsf(tau) + sqrtf(1.f + tau*tau));
                        cs = 1.f / sqrtf(1.f + t2*t2);
                        sn = t2 * cs;
                    }
                    rc[l] = cs; rs[l] = sn;
                }
                WB();
                for (int u = l; u < 72; u += 64) {
                    int pi = u / 12, k = u % 12, p, q;
                    jpair(r, pi, p, q);
                    float cs = rc[pi], sn = rs[pi];
                    float x = A[p*12 + k], y = A[q*12 + k];
                    A[p*12 + k] = cs*x - sn*y;
                    A[q*12 + k] = sn*x + cs*y;
                }
                WB();
                for (int u = l; u < 144; u += 64) {
                    int isV = (u >= 72);
                    int v2 = isV ? u - 72 : u;
                    int pi = v2 / 12, i = v2 % 12, p, q;
                    jpair(r, pi, p, q);
                    float cs = rc[pi], sn = rs[pi];
                    float* M = isV ? V : A;
                    float x = M[i*12 + p], y = M[i*12 + q];
                    M[i*12 + p] = cs*x - sn*y;
                    M[i*12 + q] = sn*x + cs*y;
                }
                WB();
            }
            if (l < 12) ws[DT_OFF + cb*12 + l] = A[l*13];
            for (int u = l; u < 144; u += 64) ws[UT_OFF + cb*144 + u] = V[u];
            float su = 0.f;
            for (int i = l; i < NN; i += 64) su += logf(Ls[(size_t)(cb*NN + i)*NN + i]);
            for (int o = 32; o; o >>= 1) su += __shfl_down(su, o, 64);
            if (l == 0) ws[ULOG_OFF + cb] = su;
            float sv = (l < 12) ? logf(Lt[cb*144 + l*13]) : 0.f;
            for (int o = 32; o; o >>= 1) sv += __shfl_down(sv, o, 64);
            if (l == 0) ws[VLOG_OFF + cb] = sv;
        }
        if (blk == NKS && t == 0) *((int*)(ws + CNT_OFF)) = 0;
    } else {
        int mb = blk - (NKS + 3);
        int base = mb * 2484;
        float mk = 0.f, dd = 0.f;
        for (int u = base + t; u < base + 2484; u += 256) {
            float m2 = (uns[u] != 0.f) ? 1.f : 0.f;
            mk += m2;
            dd += fabsf(mu[u] - tg[u]) * m2;
        }
        for (int o = 32; o; o >>= 1) {
            mk += __shfl_down(mk, o, 64);
            dd += __shfl_down(dd, o, 64);
        }
        int wv = t >> 6, l = t & 63;
        if (l == 0) { sh[wv] = mk; sh[16 + wv] = dd; }
        __syncthreads();
        if (t == 0) {
            float a = 0.f, b2 = 0.f;
            for (int q = 0; q < 4; ++q) { a += sh[q]; b2 += sh[16 + q]; }
            ws[MAEC_OFF + mb] = a;
            ws[MAEA_OFF + mb] = b2;
        }
    }
}

// kD: R10 software-pipelined 16-wide panel loop.
//  - S1: 32-col SYRK slice finalizing panel p+1's diag & solve columns
//  - combined phase: wave0 factors next diag WHILE waves 1-7 run bulk S2
//    and solve threads preload next arow
//  - solve reads ldg rows as float4
__global__ __launch_bounds__(KDT)
void kD(const float* __restrict__ sig,
        const float* __restrict__ mu,
        const float* __restrict__ tg,
        const float* __restrict__ wgt,
        float* __restrict__ ws,
        float* __restrict__ out) {
    extern __shared__ float lds[];
    float* Apk = lds;                    // TRIP
    float* W   = Apk + TRIP;             // 32*212
    float* Pt  = W + WR*WST;             // 16*244
    float* ldg = Pt + 16*PTS;            // 256
    float* dnv = ldg + 256;              // 16
    float* utl = dnv + 16;               // 12
    __shared__ int lflag;
    int t = threadIdx.x;
    int bid = blockIdx.x;
    int cj = bid >> 1, hf = bid & 1;
    int c = cj / TT, jj = cj % TT;
    float dt = ws[DT_OFF + cj];
    float sg = sig[c], sg2 = sg*sg;
    const float* KsC = ws + KS_OFF + (size_t)c*NN*NN;

    if (t < 12) utl[t] = ws[UT_OFF + c*144 + t*12 + jj];
    for (int f = t; f < QTOT; f += KDT) {
        int r = (int)((sqrtf(32.f*(float)f + 25.f) - 5.f)*0.5f);
        while ((roff(r+1) >> 2) <= f) ++r;
        while ((roff(r) >> 2) > f) --r;
        int c4 = (f - (roff(r) >> 2)) << 2;
        float4 v;
        float* ve = (float*)&v;
        #pragma unroll
        for (int e = 0; e < 4; ++e) {
            int cc = c4 + e;
            float x;
            if (r == NN) x = (cc == NN) ? 1.f : 0.f;
            else if (cc > r) x = 0.f;
            else { x = dt * KsC[r*NN + cc]; if (cc == r) x += sg2; }
            ve[e] = x;
        }
        *(float4*)(Apk + roff(r) + c4) = v;
    }
    __syncthreads();
    for (int u = t; u < WR*NN; u += KDT) {
        int wb2 = u / NN, i = u - wb2*NN;
        int b = hf*WR + wb2;
        const float4* mp = (const float4*)(mu + (size_t)(b*NN + i)*TT);
        const float4* tp = (const float4*)(tg + (size_t)(b*NN + i)*TT);
        float4 m0 = mp[0], m1 = mp[1], m2 = mp[2];
        float4 t0 = tp[0], t1 = tp[1], t2 = tp[2];
        float s = (t0.x-m0.x)*utl[0] + (t0.y-m0.y)*utl[1] + (t0.z-m0.z)*utl[2]
                + (t0.w-m0.w)*utl[3] + (t1.x-m1.x)*utl[4] + (t1.y-m1.y)*utl[5]
                + (t1.z-m1.z)*utl[6] + (t1.w-m1.w)*utl[7] + (t2.x-m2.x)*utl[8]
                + (t2.y-m2.y)*utl[9] + (t2.z-m2.z)*utl[10] + (t2.w-m2.w)*utl[11];
        W[wb2*WST + i] = s;
    }
    if (t < WR) W[t*WST + NN] = 0.f;
    __syncthreads();

    int wb = t - 192;
    float arow[16];

    auto preload = [&](int k0n) {
        int k1n = k0n + 16;
        int nA = NP - k1n;
        if (t < nA) {
            int abase = roff(k1n + t) + k0n;
            *(float4*)(arow+0)  = *(const float4*)(Apk + abase);
            *(float4*)(arow+4)  = *(const float4*)(Apk + abase + 4);
            *(float4*)(arow+8)  = *(const float4*)(Apk + abase + 8);
            *(float4*)(arow+12) = *(const float4*)(Apk + abase + 12);
        } else if (t >= 192 && t < 224) {
            int wbase = wb*WST + k0n;
            *(float4*)(arow+0)  = *(const float4*)(W + wbase);
            *(float4*)(arow+4)  = *(const float4*)(W + wbase + 4);
            *(float4*)(arow+8)  = *(const float4*)(W + wbase + 8);
            *(float4*)(arow+12) = *(const float4*)(W + wbase + 12);
        }
    };
    auto diagf = [&](int kd0) {              // wave0 only (t<64)
        int r = t;
        int rr = (r < 16) ? (kd0 + r) : kd0;
        int base = roff(rr) + kd0;
        float a[16];
        #pragma unroll
        for (int m = 0; m < 16; ++m) a[m] = Apk[base + m];
        #pragma unroll
        for (int kk = 0; kk < 16; ++kk) {
            float d = __shfl(a[kk], kk);
            float dv = 1.0f / sqrtf(d);
            if (t == 0) dnv[kk] = dv;
            if (r < 16 && r > kk) a[kk] *= dv;
            #pragma unroll
            for (int j2 = kk+1; j2 < 16; ++j2) {
                float v = __shfl(a[kk], j2);
                if (r < 16 && r > kk && j2 <= r) a[j2] -= a[kk]*v;
            }
        }
        if (r < 16) {
            #pragma unroll
            for (int m = 0; m < 16; ++m) ldg[r*16 + m] = a[m];
        }
    };
    auto tile44 = [&](int rbase, int cbase) {
        float4 acc0 = make_float4(0.f,0.f,0.f,0.f);
        float4 acc1 = acc0, acc2 = acc0, acc3 = acc0;
        #pragma unroll
        for (int kk = 0; kk < 16; ++kk) {
            const float* pr = Pt + kk*PTS;
            float4 a0 = *(const float4*)(pr + rbase);
            float4 bv = *(const float4*)(pr + cbase);
            acc0.x += a0.x*bv.x; acc0.y += a0.x*bv.y; acc0.z += a0.x*bv.z; acc0.w += a0.x*bv.w;
            acc1.x += a0.y*bv.x; acc1.y += a0.y*bv.y; acc1.z += a0.y*bv.z; acc1.w += a0.y*bv.w;
            acc2.x += a0.z*bv.x; acc2.y += a0.z*bv.y; acc2.z += a0.z*bv.z; acc2.w += a0.z*bv.w;
            acc3.x += a0.w*bv.x; acc3.y += a0.w*bv.y; acc3.z += a0.w*bv.z; acc3.w += a0.w*bv.w;
        }
        float4 accs[4] = {acc0, acc1, acc2, acc3};
        int ro = roff(rbase);
        #pragma unroll
        for (int ri = 0; ri < 4; ++ri) {
            int rho = rbase + ri;
            if (rho >= NP) {
                float* wp = W + (rho - NP)*WST + cbase;
                float4 w = *(float4*)wp;
                w.x -= accs[ri].x; w.y -= accs[ri].y; w.z -= accs[ri].z; w.w -= accs[ri].w;
                *(float4*)wp = w;
            } else if (cbase + 3 <= rho) {
                float* ap = Apk + ro + cbase;
                float4 w = *(float4*)ap;
                w.x -= accs[ri].x; w.y -= accs[ri].y; w.z -= accs[ri].z; w.w -= accs[ri].w;
                *(float4*)ap = w;
            } else if (cbase <= rho) {
                float* ap = Apk + ro;
                const float* af = (const float*)&accs[ri];
                #pragma unroll
                for (int e = 0; e < 4; ++e) {
                    int jc = cbase + e;
                    if (jc <= rho) ap[jc] -= af[e];
                }
            }
            ro += (rho + 4) & ~3;
        }
    };

    // initial: preload(0) + diag(0)
    preload(0);
    if (t < 64) diagf(0);
    __syncthreads();

    float zacc = 0.f;
    for (int p = 0; p < 13; ++p) {
        int k0v = p*16, k1v = k0v + 16;
        int nA = NP - k1v;
        bool isA = (t < nA), isW = (t >= 192 && t < 224);
        // ---- solve(p): uses preloaded arow + ldg/dnv; f4 row loads pipeline
        if (isA || isW) {
            float dnvr[16];
            *(float4*)(dnvr+0)  = *(const float4*)(dnv+0);
            *(float4*)(dnvr+4)  = *(const float4*)(dnv+4);
            *(float4*)(dnvr+8)  = *(const float4*)(dnv+8);
            *(float4*)(dnvr+12) = *(const float4*)(dnv+12);
            #pragma unroll
            for (int kk = 0; kk < 16; ++kk) {
                float lr[16];
                *(float4*)(lr+0)  = *(const float4*)(ldg + kk*16);
                *(float4*)(lr+4)  = *(const float4*)(ldg + kk*16 + 4);
                *(float4*)(lr+8)  = *(const float4*)(ldg + kk*16 + 8);
                *(float4*)(lr+12) = *(const float4*)(ldg + kk*16 + 12);
                float x = arow[kk];
                #pragma unroll
                for (int m = 0; m < kk; ++m) x -= arow[m] * lr[m];
                arow[kk] = x * dnvr[kk];
            }
            int rho = isW ? (NP + wb) : (k1v + t);
            if (isW) {
                #pragma unroll
                for (int m = 0; m < 16; ++m) zacc += arow[m]*arow[m];
            }
            #pragma unroll
            for (int m = 0; m < 16; ++m) Pt[m*PTS + rho] = arow[m];
        }
        __syncthreads();
        if (p < 12) {
            // ---- S1: cols [k1v, k1v+32), all rows (finalizes next panel cols)
            {
                int tx8 = t & 7, ty64 = t >> 3;
                int rbase = k1v + 4*ty64;
                int cbase = k1v + 4*tx8;
                if (rbase < NP + WR && cbase < NP && !(rbase + 3 < cbase))
                    tile44(rbase, cbase);
            }
            __syncthreads();
            // ---- combined: preload(p+1); wave0: diag(p+1); waves 1-7: S2(p)
            preload(k1v);
            if (t < 64) {
                diagf(k1v);
            } else {
                int ty7 = (t - 64) >> 5, tx = t & 31;
                int ncol = NP - k1v - 32;
                for (int rg = 0; rg < 224; rg += 56) {
                    int rbase = k1v + rg + 4*ty7;
                    if (rbase >= NP + WR) continue;
                    for (int cg = 0; cg < ncol; cg += 128) {
                        int cbase = k1v + 32 + cg + 4*tx;
                        if (cbase >= NP) continue;
                        if (rbase + 3 < cbase) continue;
                        tile44(rbase, cbase);
                    }
                }
            }
            __syncthreads();
        }
    }
    if (t >= 192 && t < 224)
        ws[SSQ_OFF + (cj << 6) + hf*WR + wb] = zacc;
    // last-block epilogue
    __threadfence();
    __syncthreads();
    if (t == 0) {
        int old = atomicAdd((int*)(ws + CNT_OFF), 1);
        lflag = (old == NBLK - 1) ? 1 : 0;
    }
    __syncthreads();
    if (!lflag) return;
    __threadfence();
    float* ep = Apk;
    float* nl = Apk + 640;
    const float C0 = -0.5f * 2484.0f * 1.8378770664093453f;
    for (int u = t; u < 640; u += KDT) {
        int b2 = u / NC, cc = u % NC;
        float q = 0.f;
        for (int j2 = 0; j2 < TT; ++j2) q += ws[SSQ_OFF + (cc*TT + j2)*64 + b2];
        ep[u] = C0 - 0.5f*q + 207.f*ws[VLOG_OFF + cc] + 12.f*ws[ULOG_OFF + cc]
                + logf(wgt[b2*NC + cc]);
    }
    __syncthreads();
    if (t < 64) {
        float mx = -1e30f;
        for (int cc = 0; cc < NC; ++cc) mx = fmaxf(mx, ep[t*NC + cc]);
        float s = 0.f;
        for (int cc = 0; cc < NC; ++cc) s += expf(ep[t*NC + cc] - mx);
        nl[t] = -(mx + logf(s));
    }
    __syncthreads();
    if (t < 64) {
        float v = nl[t];
        for (int o = 32; o; o >>= 1) v += __shfl_down(v, o, 64);
        if (t == 0) {
            float sm = 0.f, sa = 0.f;
            for (int q2 = 0; q2 < 64; ++q2) {
                sm += ws[MAEC_OFF + q2];
                sa += ws[MAEA_OFF + q2];
            }
            float mse = (sm > 0.f) ? sa / sm : 0.f;
            out[0] = 0.1f * (v * (1.f/64.f)) + 0.9f * mse;
        }
    }
}

extern "C" void kernel_launch(void* const* d_in, const int* in_sizes, int n_in,
                              void* d_out, int out_size, void* d_ws, size_t ws_size,
                              hipStream_t stream) {
    const float* mu  = (const float*)d_in[0];
    const float* tg  = (const float*)d_in[1];
    const float* uns = (const float*)d_in[2];
    const float* wgt = (const float*)d_in[3];
    const float* sig = (const float*)d_in[4];
    const float* Ls  = (const float*)d_in[6];
    const float* Lt  = (const float*)d_in[7];
    float* out = (float*)d_out;
    float* ws  = (float*)d_ws;

    const int kd_lds = (TRIP + WR*WST + 16*PTS + 256 + 16 + 12) * 4; // 132,080 B
    (void)hipFuncSetAttribute((const void*)kD,
                              hipFuncAttributeMaxDynamicSharedMemorySize, kd_lds);

    k1<<<NKS + 3 + 64, 256, 0, stream>>>(Ls, Lt, mu, tg, uns, ws);
    kD<<<NBLK, KDT, kd_lds, stream>>>(sig, mu, tg, wgt, ws, out);
}